// Round 4
// baseline (2155.678 us; speedup 1.0000x reference)
//
#include <hip/hip_runtime.h>
#include <hip/hip_bf16.h>

constexpr int B    = 16;
constexpr int N    = 4096;
constexpr int CIN  = 64;
constexpr int COUT = 128;
constexpr int M    = 1024;
constexpr int K    = 32;

typedef __attribute__((ext_vector_type(4))) float f32x4;

// ---------------------------------------------------------------------------
// FPS: one block per cloud, 512 threads. Writes ONLY idx (ints, to ws).
// Exact IEEE (contract off); argmax tie-break = smallest index.
// ---------------------------------------------------------------------------
__global__ __launch_bounds__(512) void fps2_kernel(const float* __restrict__ pos,
                                                   int* __restrict__ idx_out) {
#pragma clang fp contract(off)
  const int b   = blockIdx.x;
  const int tid = threadIdx.x;
  __shared__ float spx[N], spy[N], spz[N];
  __shared__ unsigned long long skey[8];
  __shared__ int slast;
  const float* p = pos + (size_t)b * (N * 3);
  for (int i = tid; i < N; i += 512) {
    spx[i] = p[3 * i + 0];
    spy[i] = p[3 * i + 1];
    spz[i] = p[3 * i + 2];
  }
  __syncthreads();

  constexpr int PPT = N / 512;  // 8
  float mind[PPT];
#pragma unroll
  for (int i = 0; i < PPT; i++) mind[i] = __builtin_inff();
  if (tid == 0) idx_out[b * M + 0] = 0;

  int last = 0;
  const int wv = tid >> 6, lane = tid & 63;
  for (int t = 1; t < M; t++) {
    const float lx = spx[last], ly = spy[last], lz = spz[last];
    unsigned long long best = 0ull;
#pragma unroll
    for (int i = 0; i < PPT; i++) {
      const int n = tid + i * 512;
      float dx = spx[n] - lx;
      float dy = spy[n] - ly;
      float dz = spz[n] - lz;
      float d = (dx * dx + dy * dy) + dz * dz;  // numpy order, no fma
      float mi = fminf(mind[i], d);
      mind[i] = mi;
      unsigned long long key = ((unsigned long long)__float_as_uint(mi) << 32) |
                               (unsigned)(0xFFFFFFFFu - (unsigned)n);
      best = key > best ? key : best;
    }
#pragma unroll
    for (int s = 32; s > 0; s >>= 1) {
      unsigned long long o = __shfl_xor(best, s, 64);
      best = o > best ? o : best;
    }
    if (lane == 0) skey[wv] = best;
    __syncthreads();
    if (tid == 0) {
      unsigned long long bb = skey[0];
#pragma unroll
      for (int i = 1; i < 8; i++) bb = skey[i] > bb ? skey[i] : bb;
      int n = (int)(0xFFFFFFFFu - (unsigned)bb);
      slast = n;
      idx_out[b * M + t] = n;
    }
    __syncthreads();
    last = slast;
  }
}

// ---------------------------------------------------------------------------
// pos gather: pout[cent,3] = pos[b, idx[cent], :]  (float32 passthrough)
// ---------------------------------------------------------------------------
__global__ __launch_bounds__(256) void pos_gather_kernel(const float* __restrict__ pos,
                                                         const int* __restrict__ idx,
                                                         float* __restrict__ pout) {
  const int cent = blockIdx.x * 256 + threadIdx.x;  // 16384
  const int b = cent >> 10;
  const int n = idx[cent];
  const float* p = pos + (size_t)b * (N * 3) + (size_t)n * 3;
  pout[(size_t)cent * 3 + 0] = p[0];
  pout[(size_t)cent * 3 + 1] = p[1];
  pout[(size_t)cent * 3 + 2] = p[2];
}

// ---------------------------------------------------------------------------
// KNN: one wave per centroid. 64 distances/lane in registers; 32 exact
// wave-argmin rounds (value, then smallest index).
// ---------------------------------------------------------------------------
__global__ __launch_bounds__(64) void knn2_kernel(const float* __restrict__ pos,
                                                  const int* __restrict__ idx,
                                                  int* __restrict__ nbr) {
#pragma clang fp contract(off)
  const int cent = blockIdx.x;
  const int lane = threadIdx.x;
  const int b = cent >> 10;
  const float* p = pos + (size_t)b * (N * 3);
  const int sel = idx[cent];
  const float qx = p[sel * 3 + 0], qy = p[sel * 3 + 1], qz = p[sel * 3 + 2];

  float d[64];
#pragma unroll
  for (int j = 0; j < 64; j++) {
    const int n = j * 64 + lane;
    float dx = qx - p[n * 3 + 0];
    float dy = qy - p[n * 3 + 1];
    float dz = qz - p[n * 3 + 2];
    d[j] = (dx * dx + dy * dy) + dz * dz;  // numpy order, no fma
  }
  for (int r = 0; r < K; r++) {
    float bv = __builtin_inff();
    int bj = 0;
#pragma unroll
    for (int j = 0; j < 64; j++) {
      bool lt = d[j] < bv;
      bv = lt ? d[j] : bv;
      bj = lt ? j : bj;
    }
    unsigned long long key = ((unsigned long long)__float_as_uint(bv) << 32) |
                             (unsigned)(bj * 64 + lane);
#pragma unroll
    for (int s = 32; s > 0; s >>= 1) {
      unsigned long long o = __shfl_xor(key, s, 64);
      key = o < key ? o : key;
    }
    const unsigned n = (unsigned)key;
    if (lane == 0) nbr[(size_t)cent * K + r] = (int)n;
    const int wl = (int)(n & 63), wj = (int)(n >> 6);
#pragma unroll
    for (int j = 0; j < 64; j++) {
      if (j == wj && lane == wl) d[j] = __builtin_inff();
    }
  }
}

// ---------------------------------------------------------------------------
// MLP: one block per centroid, 128 threads (thread = output col).
// Pure f32 VALU. Sole writer of x_out; launched last.
// ---------------------------------------------------------------------------
__global__ __launch_bounds__(128) void mlp_kernel(
    const float* __restrict__ x, const float* __restrict__ pos,
    const float* __restrict__ W1, const float* __restrict__ b1,
    const float* __restrict__ W2, const float* __restrict__ b2,
    const float* __restrict__ Wlin, const float* __restrict__ blin,
    const int* __restrict__ idx, const int* __restrict__ nbr,
    float* __restrict__ xout) {
  __shared__ float sIn[32][68];   // cols 0..66 used
  __shared__ float sH[32][132];
  __shared__ float sXsel[64];
  __shared__ int sNbr[32];
  const int cent = blockIdx.x;
  const int b = cent >> 10;
  const int tid = threadIdx.x;  // 0..127
  const int sel = idx[cent];
  if (tid < 32) sNbr[tid] = nbr[(size_t)cent * K + tid];
  if (tid < 64) sXsel[tid] = x[((size_t)b * N + sel) * CIN + tid];
  __syncthreads();

  {  // stage inputs: row r = tid>>2, 16 cols per thread
    const int r = tid >> 2, part = tid & 3;
    const int n = sNbr[r];
    const float* xr = x + ((size_t)b * N + n) * CIN + part * 16;
#pragma unroll
    for (int v = 0; v < 4; v++) {
      f32x4 vv = *(const f32x4*)(xr + v * 4);
      *(f32x4*)(&sIn[r][part * 16 + v * 4]) = vv;
    }
    if (part == 0) {
      const float* pb = pos + (size_t)b * (N * 3);
      sIn[r][64] = pb[n * 3 + 0] - pb[sel * 3 + 0];
      sIn[r][65] = pb[n * 3 + 1] - pb[sel * 3 + 1];
      sIn[r][66] = pb[n * 3 + 2] - pb[sel * 3 + 2];
      sIn[r][67] = 0.f;
    }
  }
  __syncthreads();

  const int col = tid;
  float acc[32];
#pragma unroll
  for (int r = 0; r < 32; r++) acc[r] = 0.f;

  // layer 1: k = 0..63 in groups of 4, tail 64..66
  for (int kg = 0; kg < 16; kg++) {
    const float w0 = W1[(kg * 4 + 0) * 128 + col];
    const float w1 = W1[(kg * 4 + 1) * 128 + col];
    const float w2 = W1[(kg * 4 + 2) * 128 + col];
    const float w3 = W1[(kg * 4 + 3) * 128 + col];
#pragma unroll
    for (int r = 0; r < 32; r++) {
      f32x4 iv = *(const f32x4*)(&sIn[r][kg * 4]);
      acc[r] += iv[0] * w0 + iv[1] * w1 + iv[2] * w2 + iv[3] * w3;
    }
  }
#pragma unroll
  for (int k = 64; k < 67; k++) {
    const float w = W1[k * 128 + col];
#pragma unroll
    for (int r = 0; r < 32; r++) acc[r] += sIn[r][k] * w;
  }

  // mish -> sH
  const float bb1 = b1[col];
#pragma unroll
  for (int r = 0; r < 32; r++) {
    float v = acc[r] + bb1;
    float sp_ = log1pf(expf(v));
    sH[r][col] = v * tanhf(sp_);
  }
  __syncthreads();

  // layer 2: k = 0..127 in groups of 4
#pragma unroll
  for (int r = 0; r < 32; r++) acc[r] = 0.f;
  for (int kg = 0; kg < 32; kg++) {
    const float w0 = W2[(kg * 4 + 0) * 128 + col];
    const float w1 = W2[(kg * 4 + 1) * 128 + col];
    const float w2 = W2[(kg * 4 + 2) * 128 + col];
    const float w3 = W2[(kg * 4 + 3) * 128 + col];
#pragma unroll
    for (int r = 0; r < 32; r++) {
      f32x4 hv = *(const f32x4*)(&sH[r][kg * 4]);
      acc[r] += hv[0] * w0 + hv[1] * w1 + hv[2] * w2 + hv[3] * w3;
    }
  }
  float m = acc[0];
#pragma unroll
  for (int r = 1; r < 32; r++) m = fmaxf(m, acc[r]);
  m += b2[col];

  float lin = blin[col];
  for (int kg = 0; kg < 16; kg++) {
    f32x4 xv = *(const f32x4*)(&sXsel[kg * 4]);
    lin += xv[0] * Wlin[(kg * 4 + 0) * 128 + col] + xv[1] * Wlin[(kg * 4 + 1) * 128 + col] +
           xv[2] * Wlin[(kg * 4 + 2) * 128 + col] + xv[3] * Wlin[(kg * 4 + 3) * 128 + col];
  }
  xout[(size_t)cent * 128 + col] = m + lin;
}

// ---------------------------------------------------------------------------
extern "C" void kernel_launch(void* const* d_in, const int* in_sizes, int n_in,
                              void* d_out, int out_size, void* d_ws, size_t ws_size,
                              hipStream_t stream) {
  const float* x    = (const float*)d_in[0];
  const float* pos  = (const float*)d_in[1];
  const float* W1   = (const float*)d_in[2];
  const float* b1   = (const float*)d_in[3];
  const float* W2   = (const float*)d_in[4];
  const float* b2   = (const float*)d_in[5];
  const float* Wlin = (const float*)d_in[6];
  const float* blin = (const float*)d_in[7];

  float* out  = (float*)d_out;                 // float32 outputs!
  float* xout = out;                           // [B*M*COUT] = 2,097,152 f32
  float* pout = out + (size_t)B * M * COUT;    // [B*M*3]    = 49,152 f32

  char* ws = (char*)d_ws;
  int* idx = (int*)ws;              // 64 KB
  int* nbr = (int*)(ws + 65536);    // 2 MB

  fps2_kernel<<<dim3(B), dim3(512), 0, stream>>>(pos, idx);
  pos_gather_kernel<<<dim3(64), dim3(256), 0, stream>>>(pos, idx, pout);
  knn2_kernel<<<dim3(B * M), dim3(64), 0, stream>>>(pos, idx, nbr);
  mlp_kernel<<<dim3(B * M), dim3(128), 0, stream>>>(x, pos, W1, b1, W2, b2,
                                                    Wlin, blin, idx, nbr, xout);
}

// Round 5
// 1461.218 us; speedup vs baseline: 1.4753x; 1.4753x over previous
//
#include <hip/hip_runtime.h>
#include <hip/hip_bf16.h>

constexpr int B    = 16;
constexpr int N    = 4096;
constexpr int CIN  = 64;
constexpr int COUT = 128;
constexpr int M    = 1024;
constexpr int K    = 32;

constexpr int K1  = 96;   // layer-1 MFMA K: 64 x + 3 rel + 29 zero pad
constexpr int LD1 = 104;  // sA1 row stride (pad +8)
constexpr int LD2 = 136;  // sA2 row stride (pad +8)

typedef __attribute__((ext_vector_type(8))) short short8;
typedef __attribute__((ext_vector_type(4))) float f32x4;

// RNE float->bf16 (finite values)
static __device__ __forceinline__ unsigned short f2bf(float f) {
  unsigned u = __float_as_uint(f);
  unsigned r = (u + 0x7FFFu + ((u >> 16) & 1u)) >> 16;
  return (unsigned short)r;
}

// fast mish: v * tanh(softplus(v)) == v * s/(s+2), s = u^2+2u, u = e^v
static __device__ __forceinline__ float fast_mish(float v) {
  float u = __expf(v);                 // v_exp_f32 path
  float s = u * (u + 2.0f);
  float t = s / (s + 2.0f);
  return (v > 60.f) ? v : v * t;       // overflow guard (u^2 inf)
}

// ---------------------------------------------------------------------------
// FPS: one block per cloud, 512 threads, points in REGISTERS (8/thread),
// ONE barrier per iteration (parity double-buffered skey). Writes idx + q.
// Exact IEEE (contract off); argmax tie-break = smallest index.
// ---------------------------------------------------------------------------
__global__ __launch_bounds__(512) void fps3_kernel(const float* __restrict__ pos,
                                                   int* __restrict__ idx_out,
                                                   float* __restrict__ pout) {
#pragma clang fp contract(off)
  const int b   = blockIdx.x;
  const int tid = threadIdx.x;
  __shared__ float spx[N], spy[N], spz[N];
  __shared__ unsigned long long skey[2][8];
  const float* p = pos + (size_t)b * (N * 3);
  for (int i = tid; i < N; i += 512) {
    spx[i] = p[3 * i + 0];
    spy[i] = p[3 * i + 1];
    spz[i] = p[3 * i + 2];
  }
  __syncthreads();

  constexpr int PPT = N / 512;  // 8
  float px[PPT], py[PPT], pz[PPT], mind[PPT];
  unsigned lokey[PPT];
#pragma unroll
  for (int i = 0; i < PPT; i++) {
    const int n = tid + i * 512;
    px[i] = spx[n];
    py[i] = spy[n];
    pz[i] = spz[n];
    mind[i] = __builtin_inff();
    lokey[i] = 0xFFFFFFFFu - (unsigned)n;
  }
  if (tid == 0) {
    idx_out[b * M + 0] = 0;
    pout[(size_t)(b * M + 0) * 3 + 0] = spx[0];
    pout[(size_t)(b * M + 0) * 3 + 1] = spy[0];
    pout[(size_t)(b * M + 0) * 3 + 2] = spz[0];
  }

  int last = 0;
  const int wv = tid >> 6, lane = tid & 63;
  for (int t = 1; t < M; t++) {
    const float lx = spx[last], ly = spy[last], lz = spz[last];
    unsigned long long best = 0ull;
#pragma unroll
    for (int i = 0; i < PPT; i++) {
      float dx = px[i] - lx;
      float dy = py[i] - ly;
      float dz = pz[i] - lz;
      float d = (dx * dx + dy * dy) + dz * dz;  // numpy order, no fma
      float mi = fminf(mind[i], d);
      mind[i] = mi;
      unsigned long long key = ((unsigned long long)__float_as_uint(mi) << 32) | lokey[i];
      best = key > best ? key : best;
    }
#pragma unroll
    for (int s = 32; s > 0; s >>= 1) {
      unsigned long long o = __shfl_xor(best, s, 64);
      best = o > best ? o : best;
    }
    const int par = t & 1;
    if (lane == 0) skey[par][wv] = best;
    __syncthreads();
    unsigned long long bb = skey[par][0];
#pragma unroll
    for (int i = 1; i < 8; i++) bb = skey[par][i] > bb ? skey[par][i] : bb;
    const int n = (int)(0xFFFFFFFFu - (unsigned)bb);
    if (tid == 0) {
      idx_out[b * M + t] = n;
      pout[(size_t)(b * M + t) * 3 + 0] = spx[n];
      pout[(size_t)(b * M + t) * 3 + 1] = spy[n];
      pout[(size_t)(b * M + t) * 3 + 2] = spz[n];
    }
    last = n;
  }
}

// ---------------------------------------------------------------------------
// KNN: one wave per centroid. 64 distances/lane in registers; 32 exact
// wave-argmin rounds (value, then smallest index).
// ---------------------------------------------------------------------------
__global__ __launch_bounds__(64) void knn2_kernel(const float* __restrict__ pos,
                                                  const int* __restrict__ idx,
                                                  int* __restrict__ nbr) {
#pragma clang fp contract(off)
  const int cent = blockIdx.x;
  const int lane = threadIdx.x;
  const int b = cent >> 10;
  const float* p = pos + (size_t)b * (N * 3);
  const int sel = idx[cent];
  const float qx = p[sel * 3 + 0], qy = p[sel * 3 + 1], qz = p[sel * 3 + 2];

  float d[64];
#pragma unroll
  for (int j = 0; j < 64; j++) {
    const int n = j * 64 + lane;
    float dx = qx - p[n * 3 + 0];
    float dy = qy - p[n * 3 + 1];
    float dz = qz - p[n * 3 + 2];
    d[j] = (dx * dx + dy * dy) + dz * dz;  // numpy order, no fma
  }
  for (int r = 0; r < K; r++) {
    float bv = __builtin_inff();
    int bj = 0;
#pragma unroll
    for (int j = 0; j < 64; j++) {
      bool lt = d[j] < bv;
      bv = lt ? d[j] : bv;
      bj = lt ? j : bj;
    }
    unsigned long long key = ((unsigned long long)__float_as_uint(bv) << 32) |
                             (unsigned)(bj * 64 + lane);
#pragma unroll
    for (int s = 32; s > 0; s >>= 1) {
      unsigned long long o = __shfl_xor(key, s, 64);
      key = o < key ? o : key;
    }
    const unsigned n = (unsigned)key;
    if (lane == 0) nbr[(size_t)cent * K + r] = (int)n;
    const int wl = (int)(n & 63), wj = (int)(n >> 6);
#pragma unroll
    for (int j = 0; j < 64; j++) {
      if (j == wj && lane == wl) d[j] = __builtin_inff();
    }
  }
}

// ---------------------------------------------------------------------------
// Weight prep: W1t[n][k] = bf16(W1[k][n]) for k<67 else 0   (n<128, k<96)
//              W2t[n][k] = bf16(W2[k][n])                   (n<128, k<128)
// ---------------------------------------------------------------------------
__global__ __launch_bounds__(256) void prep_weights(const float* __restrict__ W1,
                                                    const float* __restrict__ W2,
                                                    unsigned short* __restrict__ W1t,
                                                    unsigned short* __restrict__ W2t) {
  const int n = blockIdx.x;    // 128
  const int t = threadIdx.x;   // 256
  if (t < K1) {
    W1t[n * K1 + t] = (t < 67) ? f2bf(W1[t * 128 + n]) : (unsigned short)0;
  } else if (t < K1 + 128) {
    int k = t - K1;
    W2t[n * 128 + k] = f2bf(W2[k * 128 + n]);
  }
}

// ---------------------------------------------------------------------------
// Fused MLP (MFMA): 8 centroids/block, 256 threads (4 waves).
//   gather x+rel -> bf16 A1[32][96] -> MFMA W1t -> +b1 -> mish -> bf16
//   A2[32][128] -> MFMA W2t -> max over 32 rows -> +b2 + xsel@Wlin + blin.
// B-fragments read directly from global (W1t 24KB + W2t 32KB, L2-resident).
// ---------------------------------------------------------------------------
constexpr int FB_CENT = 8;
__global__ __launch_bounds__(256) void mlp_mfma_kernel(
    const float* __restrict__ x, const float* __restrict__ pos,
    const unsigned short* __restrict__ W1t, const unsigned short* __restrict__ W2t,
    const float* __restrict__ b1, const float* __restrict__ b2,
    const float* __restrict__ Wlin, const float* __restrict__ blin,
    const int* __restrict__ idx, const int* __restrict__ nbr,
    float* __restrict__ xout) {
  __shared__ unsigned short sA1[32][LD1];
  __shared__ unsigned short sA2[32][LD2];
  __shared__ float sB1[128];
  __shared__ float sAgg[2][128];
  __shared__ float sXsel[64];
  __shared__ int sNbr[K];
  const int tid  = threadIdx.x;
  const int wv   = tid >> 6;
  const int lane = tid & 63;
  const int mt   = wv & 1;           // M-tile (rows 0..15 / 16..31)
  const int ntb  = (wv >> 1) * 4;    // first of this wave's 4 N-tiles
  const int lrow = lane & 15;
  const int lk   = (lane >> 4) * 8;

  if (tid < 128) sB1[tid] = b1[tid];

  const int cent0 = blockIdx.x * FB_CENT;
  for (int c = 0; c < FB_CENT; c++) {
    const int cent = cent0 + c;
    const int b = cent >> 10;
    __syncthreads();  // protect prev iteration's sNbr/sXsel/sAgg readers
    const int sel = idx[cent];
    const float* pb = pos + (size_t)b * (N * 3);
    const float qx = pb[sel * 3 + 0], qy = pb[sel * 3 + 1], qz = pb[sel * 3 + 2];
    if (tid < K) sNbr[tid] = nbr[(size_t)cent * K + tid];
    if (tid < 64) sXsel[tid] = x[((size_t)b * N + sel) * CIN + tid];
    __syncthreads();

    {  // stage A1: 32 rows x 96 k. thread -> (row = tid>>3, k-chunk (tid&7)*8)
      const int row = tid >> 3;
      const int cg = tid & 7;
      const int n = sNbr[row];
      const float* xr = x + ((size_t)b * N + n) * CIN + cg * 8;
      f32x4 v0 = *(const f32x4*)(xr);
      f32x4 v1 = *(const f32x4*)(xr + 4);
      short8 hv;
#pragma unroll
      for (int e = 0; e < 4; e++) {
        hv[e]     = (short)f2bf(v0[e]);
        hv[e + 4] = (short)f2bf(v1[e]);
      }
      *(short8*)(&sA1[row][cg * 8]) = hv;
      if (cg == 0) {  // rel + zero pad: k = 64..95
        float rx = pb[n * 3 + 0] - qx, ry = pb[n * 3 + 1] - qy, rz = pb[n * 3 + 2] - qz;
        short8 r0 = {};
        r0[0] = (short)f2bf(rx);
        r0[1] = (short)f2bf(ry);
        r0[2] = (short)f2bf(rz);
        *(short8*)(&sA1[row][64]) = r0;
        short8 z = {};
        *(short8*)(&sA1[row][72]) = z;
        *(short8*)(&sA1[row][80]) = z;
        *(short8*)(&sA1[row][88]) = z;
      }
    }
    __syncthreads();

    // ---- layer 1 MFMA: C1[32,128] = A1[32,96] @ W1t^T ----
    f32x4 acc1[4] = {};
#pragma unroll
    for (int kc = 0; kc < 3; kc++) {
      short8 af = *(const short8*)(&sA1[mt * 16 + lrow][kc * 32 + lk]);
#pragma unroll
      for (int i = 0; i < 4; i++) {
        short8 bfr = *(const short8*)(W1t + ((size_t)((ntb + i) * 16 + lrow)) * K1 + kc * 32 + lk);
        acc1[i] = __builtin_amdgcn_mfma_f32_16x16x32_bf16(af, bfr, acc1[i], 0, 0, 0);
      }
    }
    // +b1, mish -> sA2.  C layout (m89): col = lane&15, row = (lane>>4)*4+reg
#pragma unroll
    for (int i = 0; i < 4; i++) {
      const int colI = (ntb + i) * 16 + lrow;
      const float bb = sB1[colI];
#pragma unroll
      for (int reg = 0; reg < 4; reg++) {
        const int row = mt * 16 + (lane >> 4) * 4 + reg;
        sA2[row][colI] = f2bf(fast_mish(acc1[i][reg] + bb));
      }
    }
    __syncthreads();

    // ---- layer 2 MFMA: C2[32,128] = A2[32,128] @ W2t^T ----
    f32x4 acc2[4] = {};
#pragma unroll
    for (int kc = 0; kc < 4; kc++) {
      short8 af = *(const short8*)(&sA2[mt * 16 + lrow][kc * 32 + lk]);
#pragma unroll
      for (int i = 0; i < 4; i++) {
        short8 bfr = *(const short8*)(W2t + ((size_t)((ntb + i) * 16 + lrow)) * 128 + kc * 32 + lk);
        acc2[i] = __builtin_amdgcn_mfma_f32_16x16x32_bf16(af, bfr, acc2[i], 0, 0, 0);
      }
    }
    // max over the 16 rows of this M-tile (row-mapping independent)
#pragma unroll
    for (int i = 0; i < 4; i++) {
      float pm = fmaxf(fmaxf(acc2[i][0], acc2[i][1]), fmaxf(acc2[i][2], acc2[i][3]));
      pm = fmaxf(pm, __shfl_xor(pm, 16, 64));
      pm = fmaxf(pm, __shfl_xor(pm, 32, 64));
      if (lane < 16) sAgg[mt][(ntb + i) * 16 + lane] = pm;
    }
    __syncthreads();

    if (tid < 128) {
      const int j = tid;
      float v = fmaxf(sAgg[0][j], sAgg[1][j]) + b2[j];
      float lin = blin[j];
      for (int kg = 0; kg < 16; kg++) {
        f32x4 xv = *(const f32x4*)(&sXsel[kg * 4]);
        lin += xv[0] * Wlin[(kg * 4 + 0) * 128 + j] + xv[1] * Wlin[(kg * 4 + 1) * 128 + j] +
               xv[2] * Wlin[(kg * 4 + 2) * 128 + j] + xv[3] * Wlin[(kg * 4 + 3) * 128 + j];
      }
      xout[(size_t)cent * 128 + j] = v + lin;
    }
  }
}

// ---------------------------------------------------------------------------
extern "C" void kernel_launch(void* const* d_in, const int* in_sizes, int n_in,
                              void* d_out, int out_size, void* d_ws, size_t ws_size,
                              hipStream_t stream) {
  const float* x    = (const float*)d_in[0];
  const float* pos  = (const float*)d_in[1];
  const float* W1   = (const float*)d_in[2];
  const float* b1   = (const float*)d_in[3];
  const float* W2   = (const float*)d_in[4];
  const float* b2   = (const float*)d_in[5];
  const float* Wlin = (const float*)d_in[6];
  const float* blin = (const float*)d_in[7];

  float* out  = (float*)d_out;                 // float32 outputs
  float* xout = out;                           // [B*M*COUT]
  float* pout = out + (size_t)B * M * COUT;    // [B*M*3]

  char* ws = (char*)d_ws;
  int* idx            = (int*)ws;                                         // 64 KB
  int* nbr            = (int*)(ws + 65536);                               // 2 MB
  unsigned short* W1t = (unsigned short*)(ws + 65536 + 2097152);          // 24 KB
  unsigned short* W2t = (unsigned short*)(ws + 65536 + 2097152 + 24576);  // 32 KB

  prep_weights<<<dim3(128), dim3(256), 0, stream>>>(W1, W2, W1t, W2t);
  fps3_kernel<<<dim3(B), dim3(512), 0, stream>>>(pos, idx, pout);
  knn2_kernel<<<dim3(B * M), dim3(64), 0, stream>>>(pos, idx, nbr);
  mlp_mfma_kernel<<<dim3(B * M / FB_CENT), dim3(256), 0, stream>>>(
      x, pos, W1t, W2t, b1, b2, Wlin, blin, idx, nbr, xout);
}

// Round 6
// 1172.264 us; speedup vs baseline: 1.8389x; 1.2465x over previous
//
#include <hip/hip_runtime.h>
#include <hip/hip_bf16.h>

constexpr int B    = 16;
constexpr int N    = 4096;
constexpr int CIN  = 64;
constexpr int COUT = 128;
constexpr int M    = 1024;
constexpr int K    = 32;

constexpr int K1  = 96;   // layer-1 MFMA K: 64 x + 3 rel + 29 zero pad
constexpr int LD1 = 104;  // sA1 row stride (pad +8)
constexpr int LD2 = 136;  // sA2 row stride (pad +8)

typedef __attribute__((ext_vector_type(8))) short short8;
typedef __attribute__((ext_vector_type(4))) float f32x4;

// RNE float->bf16 (finite values)
static __device__ __forceinline__ unsigned short f2bf(float f) {
  unsigned u = __float_as_uint(f);
  unsigned r = (u + 0x7FFFu + ((u >> 16) & 1u)) >> 16;
  return (unsigned short)r;
}

// fast mish: v * tanh(softplus(v)) == v * s/(s+2), s = u^2+2u, u = e^v
static __device__ __forceinline__ float fast_mish(float v) {
  float u = __expf(v);
  float s = u * (u + 2.0f);
  float t = s / (s + 2.0f);
  return (v > 60.f) ? v : v * t;
}

// ---------------------------------------------------------------------------
// Wave-wide u32 max via DPP (row_shr 1/2/4/8, row_bcast 15/31, readlane 63).
// Identity (0 or self) is safe for umax under either bound_ctrl convention.
// ---------------------------------------------------------------------------
template <int CTRL, int RM>
static __device__ __forceinline__ unsigned dpp_umax_step(unsigned x) {
  int o = __builtin_amdgcn_update_dpp((int)x, (int)x, CTRL, RM, 0xF, false);
  unsigned u = (unsigned)o;
  return x > u ? x : u;
}
static __device__ __forceinline__ unsigned wave_umax(unsigned x) {
  x = dpp_umax_step<0x111, 0xF>(x);  // row_shr:1
  x = dpp_umax_step<0x112, 0xF>(x);  // row_shr:2
  x = dpp_umax_step<0x114, 0xF>(x);  // row_shr:4
  x = dpp_umax_step<0x118, 0xF>(x);  // row_shr:8
  x = dpp_umax_step<0x142, 0xA>(x);  // row_bcast:15 -> rows 1,3
  x = dpp_umax_step<0x143, 0xC>(x);  // row_bcast:31 -> rows 2,3
  return (unsigned)__builtin_amdgcn_readlane((int)x, 63);
}

// ---------------------------------------------------------------------------
// FPS: one block per cloud, 512 threads, 8 pts/lane in registers.
// DPP wave argmax (value-bits umax, then inverted-index umax for exact numpy
// tie-break), one barrier/iter (parity skey). Writes idx + q (f32).
// ---------------------------------------------------------------------------
__global__ __launch_bounds__(512) void fps4_kernel(const float* __restrict__ pos,
                                                   int* __restrict__ idx_out,
                                                   float* __restrict__ pout) {
#pragma clang fp contract(off)
  const int b   = blockIdx.x;
  const int tid = threadIdx.x;
  __shared__ float sp[N][4];
  __shared__ unsigned long long skey[2][8];
  const float* p = pos + (size_t)b * (N * 3);
  for (int i = tid; i < N; i += 512) {
    sp[i][0] = p[3 * i + 0];
    sp[i][1] = p[3 * i + 1];
    sp[i][2] = p[3 * i + 2];
    sp[i][3] = 0.f;
  }
  __syncthreads();

  constexpr int PPT = N / 512;  // 8
  float px[PPT], py[PPT], pz[PPT], mind[PPT];
#pragma unroll
  for (int i = 0; i < PPT; i++) {
    const int n = tid + i * 512;
    px[i] = sp[n][0];
    py[i] = sp[n][1];
    pz[i] = sp[n][2];
    mind[i] = __builtin_inff();
  }
  if (tid == 0) {
    idx_out[b * M + 0] = 0;
    pout[(size_t)(b * M + 0) * 3 + 0] = sp[0][0];
    pout[(size_t)(b * M + 0) * 3 + 1] = sp[0][1];
    pout[(size_t)(b * M + 0) * 3 + 2] = sp[0][2];
  }

  int last = 0;
  const int wv = tid >> 6, lane = tid & 63;
  for (int t = 1; t < M; t++) {
    const f32x4 q = *(const f32x4*)(&sp[last][0]);
    float bv = -1.f;
    unsigned bn = 0;
#pragma unroll
    for (int i = 0; i < PPT; i++) {
      float dx = px[i] - q[0];
      float dy = py[i] - q[1];
      float dz = pz[i] - q[2];
      float d = (dx * dx + dy * dy) + dz * dz;  // numpy order, no fma
      float mi = fminf(mind[i], d);
      mind[i] = mi;
      bool c = mi > bv;  // strict: ascending n keeps smallest index on ties
      bv = c ? mi : bv;
      bn = c ? (unsigned)(tid + i * 512) : bn;
    }
    const unsigned vb = __float_as_uint(bv);           // nonneg floats: monotone bits
    const unsigned wbits = wave_umax(vb);              // wave max value
    unsigned tk = (vb == wbits) ? (0xFFFFFFFFu - bn) : 0u;
    tk = wave_umax(tk);                                // ties -> smallest n
    const int par = t & 1;
    if (lane == 0) skey[par][wv] = ((unsigned long long)wbits << 32) | tk;
    __syncthreads();
    unsigned long long bb = skey[par][0];
#pragma unroll
    for (int i = 1; i < 8; i++) {
      const unsigned long long o = skey[par][i];
      bb = o > bb ? o : bb;
    }
    const int n = (int)(0xFFFFFFFFu - (unsigned)bb);
    if (tid == 0) {
      idx_out[b * M + t] = n;
      pout[(size_t)(b * M + t) * 3 + 0] = sp[n][0];
      pout[(size_t)(b * M + t) * 3 + 1] = sp[n][1];
      pout[(size_t)(b * M + t) * 3 + 2] = sp[n][2];
    }
    last = n;
  }
}

// ---------------------------------------------------------------------------
// KNN: one wave per centroid, 4 waves/block. d[64] in registers + 8 cached
// group-minima; per round: DPP wave argmin (exact (d,n) tie-break), then only
// the winner's group of 8 is rescanned (scalar-uniform branch via readlane).
// ---------------------------------------------------------------------------
__global__ __launch_bounds__(256) void knn3_kernel(const float* __restrict__ pos,
                                                   const int* __restrict__ idx,
                                                   int* __restrict__ nbr) {
#pragma clang fp contract(off)
  const int wv   = threadIdx.x >> 6;
  const int lane = threadIdx.x & 63;
  const int cent = blockIdx.x * 4 + wv;
  const int b = cent >> 10;
  const float* p = pos + (size_t)b * (N * 3);
  const int sel = idx[cent];
  const float qx = p[sel * 3 + 0], qy = p[sel * 3 + 1], qz = p[sel * 3 + 2];

  float d[64];
#pragma unroll
  for (int j = 0; j < 64; j++) {
    const int n = j * 64 + lane;
    float dx = qx - p[n * 3 + 0];
    float dy = qy - p[n * 3 + 1];
    float dz = qz - p[n * 3 + 2];
    d[j] = (dx * dx + dy * dy) + dz * dz;  // numpy order, no fma
  }
  float gv[8];
  int gj[8];
#pragma unroll
  for (int g = 0; g < 8; g++) {
    gv[g] = __builtin_inff();
    gj[g] = 8 * g;
#pragma unroll
    for (int e = 0; e < 8; e++) {
      const int j = 8 * g + e;
      bool c = d[j] < gv[g];  // strict: ascending j keeps smallest on ties
      gv[g] = c ? d[j] : gv[g];
      gj[g] = c ? j : gj[g];
    }
  }

  int* out = nbr + (size_t)cent * K;
  for (int r = 0; r < K; r++) {
    float bv = __builtin_inff();
    int bj = 0;
#pragma unroll
    for (int g = 0; g < 8; g++) {
      bool c = gv[g] < bv;
      bv = c ? gv[g] : bv;
      bj = c ? gj[g] : bj;
    }
    const unsigned bn = (unsigned)(bj * 64 + lane);
    const unsigned nb = ~__float_as_uint(bv);  // ~bits: umax -> min distance
    const unsigned wnb = wave_umax(nb);
    unsigned tk = (nb == wnb) ? (0xFFFFFFFFu - bn) : 0u;
    tk = wave_umax(tk);                        // ties -> smallest global n
    const unsigned wn = 0xFFFFFFFFu - tk;      // uniform (SGPR via readlane)
    if (lane == 0) out[r] = (int)wn;

    const int wj = (int)(wn >> 6);
    const int wl = (int)(wn & 63);
    const int wg = wj >> 3;
#pragma unroll
    for (int g = 0; g < 8; g++) {
      if (g == wg) {  // scalar branch: only winner's group pays
#pragma unroll
        for (int e = 0; e < 8; e++) {
          if (8 * g + e == wj) {
            if (lane == wl) d[8 * g + e] = __builtin_inff();
          }
        }
        float nv = __builtin_inff();
        int nj = 8 * g;
#pragma unroll
        for (int e = 0; e < 8; e++) {
          const int j = 8 * g + e;
          bool c = d[j] < nv;
          nv = c ? d[j] : nv;
          nj = c ? j : nj;
        }
        gv[g] = nv;
        gj[g] = nj;
      }
    }
  }
}

// ---------------------------------------------------------------------------
// Weight prep: W1t[n][k] = bf16(W1[k][n]) for k<67 else 0   (n<128, k<96)
//              W2t[n][k] = bf16(W2[k][n])                   (n<128, k<128)
// ---------------------------------------------------------------------------
__global__ __launch_bounds__(256) void prep_weights(const float* __restrict__ W1,
                                                    const float* __restrict__ W2,
                                                    unsigned short* __restrict__ W1t,
                                                    unsigned short* __restrict__ W2t) {
  const int n = blockIdx.x;    // 128
  const int t = threadIdx.x;   // 256
  if (t < K1) {
    W1t[n * K1 + t] = (t < 67) ? f2bf(W1[t * 128 + n]) : (unsigned short)0;
  } else if (t < K1 + 128) {
    int k = t - K1;
    W2t[n * 128 + k] = f2bf(W2[k * 128 + n]);
  }
}

// ---------------------------------------------------------------------------
// Fused MLP (MFMA): 8 centroids/block, 256 threads (4 waves).
// ---------------------------------------------------------------------------
constexpr int FB_CENT = 8;
__global__ __launch_bounds__(256) void mlp_mfma_kernel(
    const float* __restrict__ x, const float* __restrict__ pos,
    const unsigned short* __restrict__ W1t, const unsigned short* __restrict__ W2t,
    const float* __restrict__ b1, const float* __restrict__ b2,
    const float* __restrict__ Wlin, const float* __restrict__ blin,
    const int* __restrict__ idx, const int* __restrict__ nbr,
    float* __restrict__ xout) {
  __shared__ unsigned short sA1[32][LD1];
  __shared__ unsigned short sA2[32][LD2];
  __shared__ float sB1[128];
  __shared__ float sAgg[2][128];
  __shared__ float sXsel[64];
  __shared__ int sNbr[K];
  const int tid  = threadIdx.x;
  const int wv   = tid >> 6;
  const int lane = tid & 63;
  const int mt   = wv & 1;
  const int ntb  = (wv >> 1) * 4;
  const int lrow = lane & 15;
  const int lk   = (lane >> 4) * 8;

  if (tid < 128) sB1[tid] = b1[tid];

  const int cent0 = blockIdx.x * FB_CENT;
  for (int c = 0; c < FB_CENT; c++) {
    const int cent = cent0 + c;
    const int b = cent >> 10;
    __syncthreads();
    const int sel = idx[cent];
    const float* pb = pos + (size_t)b * (N * 3);
    const float qx = pb[sel * 3 + 0], qy = pb[sel * 3 + 1], qz = pb[sel * 3 + 2];
    if (tid < K) sNbr[tid] = nbr[(size_t)cent * K + tid];
    if (tid < 64) sXsel[tid] = x[((size_t)b * N + sel) * CIN + tid];
    __syncthreads();

    {
      const int row = tid >> 3;
      const int cg = tid & 7;
      const int n = sNbr[row];
      const float* xr = x + ((size_t)b * N + n) * CIN + cg * 8;
      f32x4 v0 = *(const f32x4*)(xr);
      f32x4 v1 = *(const f32x4*)(xr + 4);
      short8 hv;
#pragma unroll
      for (int e = 0; e < 4; e++) {
        hv[e]     = (short)f2bf(v0[e]);
        hv[e + 4] = (short)f2bf(v1[e]);
      }
      *(short8*)(&sA1[row][cg * 8]) = hv;
      if (cg == 0) {
        float rx = pb[n * 3 + 0] - qx, ry = pb[n * 3 + 1] - qy, rz = pb[n * 3 + 2] - qz;
        short8 r0 = {};
        r0[0] = (short)f2bf(rx);
        r0[1] = (short)f2bf(ry);
        r0[2] = (short)f2bf(rz);
        *(short8*)(&sA1[row][64]) = r0;
        short8 z = {};
        *(short8*)(&sA1[row][72]) = z;
        *(short8*)(&sA1[row][80]) = z;
        *(short8*)(&sA1[row][88]) = z;
      }
    }
    __syncthreads();

    f32x4 acc1[4] = {};
#pragma unroll
    for (int kc = 0; kc < 3; kc++) {
      short8 af = *(const short8*)(&sA1[mt * 16 + lrow][kc * 32 + lk]);
#pragma unroll
      for (int i = 0; i < 4; i++) {
        short8 bfr = *(const short8*)(W1t + ((size_t)((ntb + i) * 16 + lrow)) * K1 + kc * 32 + lk);
        acc1[i] = __builtin_amdgcn_mfma_f32_16x16x32_bf16(af, bfr, acc1[i], 0, 0, 0);
      }
    }
#pragma unroll
    for (int i = 0; i < 4; i++) {
      const int colI = (ntb + i) * 16 + lrow;
      const float bb = sB1[colI];
#pragma unroll
      for (int reg = 0; reg < 4; reg++) {
        const int row = mt * 16 + (lane >> 4) * 4 + reg;
        sA2[row][colI] = f2bf(fast_mish(acc1[i][reg] + bb));
      }
    }
    __syncthreads();

    f32x4 acc2[4] = {};
#pragma unroll
    for (int kc = 0; kc < 4; kc++) {
      short8 af = *(const short8*)(&sA2[mt * 16 + lrow][kc * 32 + lk]);
#pragma unroll
      for (int i = 0; i < 4; i++) {
        short8 bfr = *(const short8*)(W2t + ((size_t)((ntb + i) * 16 + lrow)) * 128 + kc * 32 + lk);
        acc2[i] = __builtin_amdgcn_mfma_f32_16x16x32_bf16(af, bfr, acc2[i], 0, 0, 0);
      }
    }
#pragma unroll
    for (int i = 0; i < 4; i++) {
      float pm = fmaxf(fmaxf(acc2[i][0], acc2[i][1]), fmaxf(acc2[i][2], acc2[i][3]));
      pm = fmaxf(pm, __shfl_xor(pm, 16, 64));
      pm = fmaxf(pm, __shfl_xor(pm, 32, 64));
      if (lane < 16) sAgg[mt][(ntb + i) * 16 + lane] = pm;
    }
    __syncthreads();

    if (tid < 128) {
      const int j = tid;
      float v = fmaxf(sAgg[0][j], sAgg[1][j]) + b2[j];
      float lin = blin[j];
      for (int kg = 0; kg < 16; kg++) {
        f32x4 xv = *(const f32x4*)(&sXsel[kg * 4]);
        lin += xv[0] * Wlin[(kg * 4 + 0) * 128 + j] + xv[1] * Wlin[(kg * 4 + 1) * 128 + j] +
               xv[2] * Wlin[(kg * 4 + 2) * 128 + j] + xv[3] * Wlin[(kg * 4 + 3) * 128 + j];
      }
      xout[(size_t)cent * 128 + j] = v + lin;
    }
  }
}

// ---------------------------------------------------------------------------
extern "C" void kernel_launch(void* const* d_in, const int* in_sizes, int n_in,
                              void* d_out, int out_size, void* d_ws, size_t ws_size,
                              hipStream_t stream) {
  const float* x    = (const float*)d_in[0];
  const float* pos  = (const float*)d_in[1];
  const float* W1   = (const float*)d_in[2];
  const float* b1   = (const float*)d_in[3];
  const float* W2   = (const float*)d_in[4];
  const float* b2   = (const float*)d_in[5];
  const float* Wlin = (const float*)d_in[6];
  const float* blin = (const float*)d_in[7];

  float* out  = (float*)d_out;                 // float32 outputs
  float* xout = out;                           // [B*M*COUT]
  float* pout = out + (size_t)B * M * COUT;    // [B*M*3]

  char* ws = (char*)d_ws;
  int* idx            = (int*)ws;                                         // 64 KB
  int* nbr            = (int*)(ws + 65536);                               // 2 MB
  unsigned short* W1t = (unsigned short*)(ws + 65536 + 2097152);          // 24 KB
  unsigned short* W2t = (unsigned short*)(ws + 65536 + 2097152 + 24576);  // 32 KB

  prep_weights<<<dim3(128), dim3(256), 0, stream>>>(W1, W2, W1t, W2t);
  fps4_kernel<<<dim3(B), dim3(512), 0, stream>>>(pos, idx, pout);
  knn3_kernel<<<dim3(B * M / 4), dim3(256), 0, stream>>>(pos, idx, nbr);
  mlp_mfma_kernel<<<dim3(B * M / FB_CENT), dim3(256), 0, stream>>>(
      x, pos, W1t, W2t, b1, b2, Wlin, blin, idx, nbr, xout);
}